// Round 4
// 1311.863 us; speedup vs baseline: 1.1401x; 1.1401x over previous
//
#include <hip/hip_runtime.h>

// PricePredictionModel: 2-layer LSTM encoder (T=512) + 2-layer LSTM decoder (64) + linear head.
// B=2048, H=128, 4H=512. Round-17 = r13 (verified 1495us) with a BIT-IDENTICAL re-pipelining:
// merged encoder super-step. r13 did {MFMA0;upd0;BAR;MFMA1;upd1;BAR} because cell1 read h0 of
// the SAME t. But cell1(t=S) needs only h0[S], h1[S-1] — both from the previous step's buffers.
// So: prologue computes h0[0]; super-step S computes cell1(t=S) AND cell0(t=S+1) reading only
// p-buffers, writes both to np, ONE barrier. 1024 -> ~522 barriers. Same ops, same operands,
// same per-value accumulation order => absmax must equal baseline 4.882812e-4 exactly.
// Also: xch stored transposed [t][b] (kills the 8-way bank alias on per-step x reads).
// Decoder unchanged (pred feedback is sequential) with split parities p0/p1 for the handoff.
// NO math changes (r14/r15 lesson: any ulp deviation in gates fails accuracy).
// Predicted: dur ~1400-1440us, VALUBusy 55->~59%, absmax exactly 4.882812e-4.

typedef _Float16 half_t;
typedef _Float16 f16x8 __attribute__((ext_vector_type(8)));
typedef float    f32x4 __attribute__((ext_vector_type(4)));

#define BT   8
#define H    128
#define T    512
#define OUTS 64

__device__ __forceinline__ float sigm(float x)   { return 1.0f / (1.0f + __expf(-x)); }
__device__ __forceinline__ float tanh_f(float x) { return 2.0f / (1.0f + __expf(-2.0f * x)) - 1.0f; }

// MFMA with B in AGPR class (weights resident in the acc file)
__device__ __forceinline__ void mfma_a(f32x4& d, f16x8 a, const f16x8& b) {
  asm("v_mfma_f32_16x16x32_f16 %0, %1, %2, %0" : "+v"(d) : "v"(a), "a"(b));
}
// MFMA with B in arch-VGPR class
__device__ __forceinline__ void mfma_v(f32x4& d, f16x8 a, const f16x8& b) {
  asm("v_mfma_f32_16x16x32_f16 %0, %1, %2, %0" : "+v"(d) : "v"(a), "v"(b));
}

// A-fragment read from swizzled h buffer: tile row = col (0..15) -> batch b = col>>1
// (tile-row pairs duplicated). element jj = h[b][kb*32 + kg*8 + jj]; byte col XOR-swizzled by b<<4.
__device__ __forceinline__ f16x8 lda(const half_t* buf, int col, int kg, int kb) {
  int b  = col >> 1;
  int bc = (kb * 64 + kg * 16) ^ (b << 4);
  return *(const f16x8*)((const char*)buf + b * 256 + bc);
}

// write h (fp32 -> fp16) into swizzled buffer at (b, j)
__device__ __forceinline__ void wr_h(half_t* hb, int b, int j, float h) {
  int bc = (j * 2) ^ (b << 4);
  *(half_t*)((char*)hb + b * 256 + bc) = (half_t)h;
}

// AGPR-matrix pass M (0=Whh0-slot, 1=Wih1-slot): acc[jt][q] += A(buf) * Wa[M]  (32 MFMAs)
template <int M>
__device__ __forceinline__ void pass_a(f32x4 (&acc)[2][4], const f16x8 (&wa)[2][4][2][4],
                                       const half_t* buf, int col, int kg) {
#pragma unroll
  for (int kb = 0; kb < 4; kb++) {
    f16x8 a = lda(buf, col, kg, kb);
#pragma unroll
    for (int jt = 0; jt < 2; jt++)
#pragma unroll
      for (int q = 0; q < 4; q++)
        mfma_a(acc[jt][q], a, wa[M][q][jt][kb]);
  }
}

// VGPR-matrix pass (Whh1-slot): acc[jt][q] += A(buf) * Wv  (32 MFMAs)
__device__ __forceinline__ void pass_v(f32x4 (&acc)[2][4], const f16x8 (&wv2)[4][2][4],
                                       const half_t* buf, int col, int kg) {
#pragma unroll
  for (int kb = 0; kb < 4; kb++) {
    f16x8 a = lda(buf, col, kg, kb);
#pragma unroll
    for (int jt = 0; jt < 2; jt++)
#pragma unroll
      for (int q = 0; q < 4; q++)
        mfma_v(acc[jt][q], a, wv2[q][jt][kb]);
  }
}

__device__ __forceinline__ void zacc(f32x4 (&acc)[2][4]) {
#pragma unroll
  for (int jt = 0; jt < 2; jt++)
#pragma unroll
    for (int q = 0; q < 4; q++) acc[jt][q] = (f32x4){0.f, 0.f, 0.f, 0.f};
}

// load the two AGPR-resident matrices (base+0, base+1) and pin to the acc file
__device__ __forceinline__ void load_wa(f16x8 (&wa)[2][4][2][4], const half_t* w16,
                                        int base, int wv, int col, int kg) {
#pragma unroll
  for (int m = 0; m < 2; m++)
#pragma unroll
    for (int q = 0; q < 4; q++)
#pragma unroll
      for (int jt = 0; jt < 2; jt++)
#pragma unroll
        for (int kb = 0; kb < 4; kb++) {
          wa[m][q][jt][kb] = *(const f16x8*)(w16 + (size_t)(base + m) * 65536 +
                                             (size_t)(q * 128 + wv * 32 + jt * 16 + col) * 128 +
                                             kb * 32 + kg * 8);
          asm("" : "+a"(wa[m][q][jt][kb]));
        }
}

// load the VGPR-resident matrix (base+2)
__device__ __forceinline__ void load_wv(f16x8 (&wv2)[4][2][4], const half_t* w16,
                                        int base, int wv, int col, int kg) {
#pragma unroll
  for (int q = 0; q < 4; q++)
#pragma unroll
    for (int jt = 0; jt < 2; jt++)
#pragma unroll
      for (int kb = 0; kb < 4; kb++)
        wv2[q][jt][kb] = *(const f16x8*)(w16 + (size_t)(base + 2) * 65536 +
                                         (size_t)(q * 128 + wv * 32 + jt * 16 + col) * 128 +
                                         kb * 32 + kg * 8);
}

// prep: fp32->fp16 weights (6 x [512][128]) + transposed combined biases biasT[set][j][4]
// + transposed input-weight cols xwT[phase][j][4]
__global__ void prep_kernel(const float* m0, const float* m1, const float* m2,
                            const float* m3, const float* m4, const float* m5,
                            const float* ba0, const float* bb0, const float* ba1, const float* bb1,
                            const float* ba2, const float* bb2, const float* ba3, const float* bb3,
                            const float* encWih0, const float* decWih0,
                            half_t* w16, float* biasT, float* xwT) {
  int i = blockIdx.x * 256 + threadIdx.x;
  if (i < 6 * 65536) {
    int m = i >> 16, e = i & 65535;
    const float* src = (m == 0) ? m0 : (m == 1) ? m1 : (m == 2) ? m2
                     : (m == 3) ? m3 : (m == 4) ? m4 : m5;
    w16[i] = (half_t)src[e];
  }
  if (i < 2048) {
    int set = i >> 9, wi = i & 511, q = wi >> 7, jh = wi & 127;
    const float* A  = (set == 0) ? ba0 : (set == 1) ? ba1 : (set == 2) ? ba2 : ba3;
    const float* Bv = (set == 0) ? bb0 : (set == 1) ? bb1 : (set == 2) ? bb2 : bb3;
    biasT[set * 512 + jh * 4 + q] = A[wi] + Bv[wi];
  }
  if (i < 1024) {
    int ph = i >> 9, wi = i & 511, q = wi >> 7, jh = wi & 127;
    xwT[ph * 512 + jh * 4 + q] = (ph ? decWih0 : encWih0)[wi];
  }
}

__global__ __launch_bounds__(256, 1)
void lstm_all(const float* __restrict__ x,        // [2048][512]
              const float* __restrict__ linW,     // [128]
              const float* __restrict__ linb,     // [1]
              const half_t* __restrict__ w16,     // 6 x [512][128] fp16
              const float* __restrict__ biasTg,   // [4][128][4]
              const float* __restrict__ xwTg,     // [2][128][4]
              float* __restrict__ out)            // [2048][64]
{
  __shared__ alignas(16) half_t h0b[2][BT * H];
  __shared__ alignas(16) half_t h1b[2][BT * H];   // 8 KB
  __shared__ float xch[64 * BT];                  // 2 KB, TRANSPOSED [t&63][b]
  __shared__ float h1f[BT * H];                   // 4 KB
  __shared__ float linWs[H];
  __shared__ float pp[256];
  __shared__ float predbuf[BT];

  const int tid  = threadIdx.x;
  const int wv   = tid >> 6;         // 0..3, owns j in [32wv, 32wv+32)
  const int lane = tid & 63;
  const int col  = lane & 15;
  const int kg   = lane >> 4;
  const int b0   = blockIdx.x * BT;

  for (int z = tid; z < 1024; z += 256) {
    ((unsigned*)h0b)[z] = 0u; ((unsigned*)h1b)[z] = 0u;
  }
  if (tid < H) linWs[tid] = linW[tid];

  // weights: wa = {Whh0, Wih1} AGPR-pinned (256 regs), wv2 = Whh1 arch VGPRs (128 regs)
  f16x8 wa[2][4][2][4];
  f16x8 wv2[4][2][4];
  load_wa(wa, w16, 0, wv, col, kg);
  load_wv(wv2, w16, 0, wv, col, kg);

  // biases + x-weights in registers (post-MFMA fp32 add, r10 numeric order)
  float b0r[2][4], b1r[2][4], xwr[2][4];
#pragma unroll
  for (int jt = 0; jt < 2; jt++) {
    const int jj = wv * 32 + jt * 16 + col;
#pragma unroll
    for (int q = 0; q < 4; q++) {
      b0r[jt][q] = biasTg[jj * 4 + q];
      b1r[jt][q] = biasTg[512 + jj * 4 + q];
      xwr[jt][q] = xwTg[jj * 4 + q];
    }
  }

  // 2 sites/lane/jt: b = 2*kg + s, acc element e = 2*s (even tile rows)
  float c0[2][2] = {{0, 0}, {0, 0}};
  float c1[2][2] = {{0, 0}, {0, 0}};

  // chunk 0 of x, transposed: xch[j*8+b] = x[b][j]
  for (int e = tid; e < BT * 64; e += 256) {
    int b = e >> 6, j = e & 63;
    xch[j * 8 + b] = x[(size_t)(b0 + b) * T + j];
  }
  __syncthreads();

  // ========== encoder prologue: cell0 t=0 (h0 prev = zeros) ==========
  {
    f32x4 acc[2][4];
    zacc(acc);
    pass_a<0>(acc, wa, h0b[0], col, kg);
#pragma unroll
    for (int jt = 0; jt < 2; jt++) {
      const int jj = wv * 32 + jt * 16 + col;
#pragma unroll
      for (int s = 0; s < 2; s++) {
        const int b = 2 * kg + s;
        const int e = 2 * s;
        float xv = xch[0 * 8 + b];
        float gi = acc[jt][0][e] + b0r[jt][0] + xv * xwr[jt][0];
        float gf = acc[jt][1][e] + b0r[jt][1] + xv * xwr[jt][1];
        float gg = acc[jt][2][e] + b0r[jt][2] + xv * xwr[jt][2];
        float go = acc[jt][3][e] + b0r[jt][3] + xv * xwr[jt][3];
        float cn = sigm(gf) * c0[jt][s] + sigm(gi) * tanh_f(gg);
        c0[jt][s] = cn;
        wr_h(h0b[1], b, jj, sigm(go) * tanh_f(cn));
      }
    }
  }
  __syncthreads();
  int p = 1;

  // ========== merged super-steps S=0..510: cell1(t=S) + cell0(t=S+1), 1 barrier ==========
  for (int S = 0; S < 511; S++) {
    if (((S + 1) & 63) == 0) {           // refill x chunk (S+1)>>6 (7 times)
      const int ch = (S + 1) >> 6;
      for (int e = tid; e < BT * 64; e += 256) {
        int b = e >> 6, j = e & 63;
        xch[j * 8 + b] = x[(size_t)(b0 + b) * T + ch * 64 + j];
      }
      __syncthreads();
    }
    const int np = p ^ 1;
    f32x4 acc[2][4];
    // ---- cell 1 (t=S): h1[S-1] @ Whh1^T + h0[S] @ Wih1^T (r13 pass order) ----
    zacc(acc);
    pass_v(acc, wv2, h1b[p], col, kg);
    pass_a<1>(acc, wa, h0b[p], col, kg);
#pragma unroll
    for (int jt = 0; jt < 2; jt++) {
      const int jj = wv * 32 + jt * 16 + col;
#pragma unroll
      for (int s = 0; s < 2; s++) {
        const int b = 2 * kg + s;
        const int e = 2 * s;
        float gi = acc[jt][0][e] + b1r[jt][0];
        float gf = acc[jt][1][e] + b1r[jt][1];
        float gg = acc[jt][2][e] + b1r[jt][2];
        float go = acc[jt][3][e] + b1r[jt][3];
        float cn = sigm(gf) * c1[jt][s] + sigm(gi) * tanh_f(gg);
        c1[jt][s] = cn;
        wr_h(h1b[np], b, jj, sigm(go) * tanh_f(cn));
      }
    }
    // ---- cell 0 (t=S+1): h0[S] @ Whh0^T ----
    zacc(acc);
    pass_a<0>(acc, wa, h0b[p], col, kg);
#pragma unroll
    for (int jt = 0; jt < 2; jt++) {
      const int jj = wv * 32 + jt * 16 + col;
#pragma unroll
      for (int s = 0; s < 2; s++) {
        const int b = 2 * kg + s;
        const int e = 2 * s;
        float xv = xch[((S + 1) & 63) * 8 + b];
        float gi = acc[jt][0][e] + b0r[jt][0] + xv * xwr[jt][0];
        float gf = acc[jt][1][e] + b0r[jt][1] + xv * xwr[jt][1];
        float gg = acc[jt][2][e] + b0r[jt][2] + xv * xwr[jt][2];
        float go = acc[jt][3][e] + b0r[jt][3] + xv * xwr[jt][3];
        float cn = sigm(gf) * c0[jt][s] + sigm(gi) * tanh_f(gg);
        c0[jt][s] = cn;
        wr_h(h0b[np], b, jj, sigm(go) * tanh_f(cn));
      }
    }
    __syncthreads();   // h1[S], h0[S+1] visible; p-buffers reusable
    p = np;
  }

  // ========== encoder epilogue: cell1 t=511 ==========
  {
    const int np = p ^ 1;
    f32x4 acc[2][4];
    zacc(acc);
    pass_v(acc, wv2, h1b[p], col, kg);
    pass_a<1>(acc, wa, h0b[p], col, kg);
#pragma unroll
    for (int jt = 0; jt < 2; jt++) {
      const int jj = wv * 32 + jt * 16 + col;
#pragma unroll
      for (int s = 0; s < 2; s++) {
        const int b = 2 * kg + s;
        const int e = 2 * s;
        float gi = acc[jt][0][e] + b1r[jt][0];
        float gf = acc[jt][1][e] + b1r[jt][1];
        float gg = acc[jt][2][e] + b1r[jt][2];
        float go = acc[jt][3][e] + b1r[jt][3];
        float cn = sigm(gf) * c1[jt][s] + sigm(gi) * tanh_f(gg);
        c1[jt][s] = cn;
        wr_h(h1b[np], b, jj, sigm(go) * tanh_f(cn));
      }
    }
    __syncthreads();
  }
  int p0 = p;       // h0[511] lives in h0b[p]
  int p1 = p ^ 1;   // h1[511] lives in h1b[p^1]

  // ================= decoder: 64 steps (r13 structure, split parities) =================
  load_wa(wa, w16, 3, wv, col, kg);  // 3=dec_Whh0, 4=dec_Wih1
  load_wv(wv2, w16, 3, wv, col, kg); // 5=dec_Whh1
#pragma unroll
  for (int jt = 0; jt < 2; jt++) {
    const int jj = wv * 32 + jt * 16 + col;
#pragma unroll
    for (int q = 0; q < 4; q++) {
      b0r[jt][q] = biasTg[1024 + jj * 4 + q];
      b1r[jt][q] = biasTg[1536 + jj * 4 + q];
      xwr[jt][q] = xwTg[512 + jj * 4 + q];
    }
  }
  const float lb = linb[0];
  if (tid < BT) predbuf[tid] = x[(size_t)(b0 + tid) * T + (T - 1)];
  __syncthreads();

  for (int so = 0; so < OUTS; so++) {
    const int n0 = p0 ^ 1, n1 = p1 ^ 1;
    f32x4 acc[2][4];
    zacc(acc);
    pass_a<0>(acc, wa, h0b[p0], col, kg);
#pragma unroll
    for (int jt = 0; jt < 2; jt++) {
      const int jj = wv * 32 + jt * 16 + col;
#pragma unroll
      for (int s = 0; s < 2; s++) {
        const int b = 2 * kg + s;
        const int e = 2 * s;
        float xv = predbuf[b];
        float gi = acc[jt][0][e] + b0r[jt][0] + xv * xwr[jt][0];
        float gf = acc[jt][1][e] + b0r[jt][1] + xv * xwr[jt][1];
        float gg = acc[jt][2][e] + b0r[jt][2] + xv * xwr[jt][2];
        float go = acc[jt][3][e] + b0r[jt][3] + xv * xwr[jt][3];
        float cn = sigm(gf) * c0[jt][s] + sigm(gi) * tanh_f(gg);
        c0[jt][s] = cn;
        wr_h(h0b[n0], b, jj, sigm(go) * tanh_f(cn));
      }
    }
    __syncthreads();
    zacc(acc);
    pass_v(acc, wv2, h1b[p1], col, kg);
    pass_a<1>(acc, wa, h0b[n0], col, kg);
#pragma unroll
    for (int jt = 0; jt < 2; jt++) {
      const int jj = wv * 32 + jt * 16 + col;
#pragma unroll
      for (int s = 0; s < 2; s++) {
        const int b = 2 * kg + s;
        const int e = 2 * s;
        float cn = sigm(acc[jt][1][e] + b1r[jt][1]) * c1[jt][s]
                 + sigm(acc[jt][0][e] + b1r[jt][0]) * tanh_f(acc[jt][2][e] + b1r[jt][2]);
        c1[jt][s] = cn;
        float hn = sigm(acc[jt][3][e] + b1r[jt][3]) * tanh_f(cn);
        wr_h(h1b[n1], b, jj, hn);
        h1f[b * H + jj] = hn;
      }
    }
    __syncthreads();
    // pred = h1 @ linW + lin_b (256 threads: 8 rows x 32 segs of 4)
    {
      int r = tid >> 5, seg = tid & 31;
      float pv = 0.0f;
#pragma unroll
      for (int kk = 0; kk < 4; kk++) pv += h1f[r * H + seg * 4 + kk] * linWs[seg * 4 + kk];
      pp[tid] = pv;
    }
    __syncthreads();
    if (tid < BT) {
      float pv = lb;
#pragma unroll
      for (int g2 = 0; g2 < 32; g2++) pv += pp[tid * 32 + g2];
      predbuf[tid] = pv;
      out[(size_t)(b0 + tid) * OUTS + so] = pv;
    }
    __syncthreads();
    p0 = n0; p1 = n1;
  }
}

extern "C" void kernel_launch(void* const* d_in, const int* in_sizes, int n_in,
                              void* d_out, int out_size, void* d_ws, size_t ws_size,
                              hipStream_t stream) {
  const float* x        = (const float*)d_in[0];
  const float* encWih0  = (const float*)d_in[1];
  const float* encWhh0  = (const float*)d_in[2];
  const float* encbih0  = (const float*)d_in[3];
  const float* encbhh0  = (const float*)d_in[4];
  const float* encWih1  = (const float*)d_in[5];
  const float* encWhh1  = (const float*)d_in[6];
  const float* encbih1  = (const float*)d_in[7];
  const float* encbhh1  = (const float*)d_in[8];
  const float* decWih0  = (const float*)d_in[9];
  const float* decWhh0  = (const float*)d_in[10];
  const float* decbih0  = (const float*)d_in[11];
  const float* decbhh0  = (const float*)d_in[12];
  const float* decWih1  = (const float*)d_in[13];
  const float* decWhh1  = (const float*)d_in[14];
  const float* decbih1  = (const float*)d_in[15];
  const float* decbhh1  = (const float*)d_in[16];
  const float* linW     = (const float*)d_in[17];
  const float* linb     = (const float*)d_in[18];

  half_t* w16  = (half_t*)d_ws;                                   // 786432 B
  float*  biasT = (float*)((char*)d_ws + (size_t)6 * 65536 * 2);  // 2048 f32
  float*  xwT   = biasT + 2048;                                   // 1024 f32

  prep_kernel<<<1536, 256, 0, stream>>>(encWhh0, encWih1, encWhh1, decWhh0, decWih1, decWhh1,
                                        encbih0, encbhh0, encbih1, encbhh1,
                                        decbih0, decbhh0, decbih1, decbhh1,
                                        encWih0, decWih0, w16, biasT, xwT);
  lstm_all<<<256, 256, 0, stream>>>(x, linW, linb, w16, biasT, xwT, (float*)d_out);
}

// Round 5
// 1311.473 us; speedup vs baseline: 1.1404x; 1.0003x over previous
//
#include <hip/hip_runtime.h>

// PricePredictionModel: 2-layer LSTM encoder (T=512) + 2-layer LSTM decoder (64) + linear head.
// B=2048, H=128, 4H=512. Round-18: r17 (verified 1311us, merged super-step) + a GUARDED
// 2-wave/SIMD variant. lstm_all8: 512 threads (8 waves), j-split 8-way (16 cols/wave), all
// three matrices AGPR-pinned (192 regs) + acc 16 + ~50 misc => ~250 <= 256 cap (512,2).
// Same per-value op order as r17 (kb-chain, pass order, update math) => bit-exact.
// r16's all-zero failure is diagnosed as hipErrorLaunchOutOfResources (regs > 256 with
// 512-thread blocks => launch silently fails). So kernel_launch probes the 512 variant with
// hipFuncGetAttributes (no spill: localSizeBytes==0) and occupancy>=1; else falls back to
// the byte-identical r17 kernel (1311us). Zero regression risk, upside ~1.4x.
// Predicted fast path: Occupancy ~23%, VALUBusy ~75%, dur ~900-1000us, absmax 4.882812e-4.

typedef _Float16 half_t;
typedef _Float16 f16x8 __attribute__((ext_vector_type(8)));
typedef float    f32x4 __attribute__((ext_vector_type(4)));

#define BT   8
#define H    128
#define T    512
#define OUTS 64

__device__ __forceinline__ float sigm(float x)   { return 1.0f / (1.0f + __expf(-x)); }
__device__ __forceinline__ float tanh_f(float x) { return 2.0f / (1.0f + __expf(-2.0f * x)) - 1.0f; }

// MFMA with B in AGPR class (weights resident in the acc file)
__device__ __forceinline__ void mfma_a(f32x4& d, f16x8 a, const f16x8& b) {
  asm("v_mfma_f32_16x16x32_f16 %0, %1, %2, %0" : "+v"(d) : "v"(a), "a"(b));
}
// MFMA with B in arch-VGPR class
__device__ __forceinline__ void mfma_v(f32x4& d, f16x8 a, const f16x8& b) {
  asm("v_mfma_f32_16x16x32_f16 %0, %1, %2, %0" : "+v"(d) : "v"(a), "v"(b));
}

// A-fragment read from swizzled h buffer: tile row = col (0..15) -> batch b = col>>1
// (tile-row pairs duplicated). element jj = h[b][kb*32 + kg*8 + jj]; byte col XOR-swizzled by b<<4.
__device__ __forceinline__ f16x8 lda(const half_t* buf, int col, int kg, int kb) {
  int b  = col >> 1;
  int bc = (kb * 64 + kg * 16) ^ (b << 4);
  return *(const f16x8*)((const char*)buf + b * 256 + bc);
}

// write h (fp32 -> fp16) into swizzled buffer at (b, j)
__device__ __forceinline__ void wr_h(half_t* hb, int b, int j, float h) {
  int bc = (j * 2) ^ (b << 4);
  *(half_t*)((char*)hb + b * 256 + bc) = (half_t)h;
}

// ---------------- 4-wave (r17) fragment machinery ----------------
template <int M>
__device__ __forceinline__ void pass_a(f32x4 (&acc)[2][4], const f16x8 (&wa)[2][4][2][4],
                                       const half_t* buf, int col, int kg) {
#pragma unroll
  for (int kb = 0; kb < 4; kb++) {
    f16x8 a = lda(buf, col, kg, kb);
#pragma unroll
    for (int jt = 0; jt < 2; jt++)
#pragma unroll
      for (int q = 0; q < 4; q++)
        mfma_a(acc[jt][q], a, wa[M][q][jt][kb]);
  }
}

__device__ __forceinline__ void pass_v(f32x4 (&acc)[2][4], const f16x8 (&wv2)[4][2][4],
                                       const half_t* buf, int col, int kg) {
#pragma unroll
  for (int kb = 0; kb < 4; kb++) {
    f16x8 a = lda(buf, col, kg, kb);
#pragma unroll
    for (int jt = 0; jt < 2; jt++)
#pragma unroll
      for (int q = 0; q < 4; q++)
        mfma_v(acc[jt][q], a, wv2[q][jt][kb]);
  }
}

__device__ __forceinline__ void zacc(f32x4 (&acc)[2][4]) {
#pragma unroll
  for (int jt = 0; jt < 2; jt++)
#pragma unroll
    for (int q = 0; q < 4; q++) acc[jt][q] = (f32x4){0.f, 0.f, 0.f, 0.f};
}

__device__ __forceinline__ void load_wa(f16x8 (&wa)[2][4][2][4], const half_t* w16,
                                        int base, int wv, int col, int kg) {
#pragma unroll
  for (int m = 0; m < 2; m++)
#pragma unroll
    for (int q = 0; q < 4; q++)
#pragma unroll
      for (int jt = 0; jt < 2; jt++)
#pragma unroll
        for (int kb = 0; kb < 4; kb++) {
          wa[m][q][jt][kb] = *(const f16x8*)(w16 + (size_t)(base + m) * 65536 +
                                             (size_t)(q * 128 + wv * 32 + jt * 16 + col) * 128 +
                                             kb * 32 + kg * 8);
          asm("" : "+a"(wa[m][q][jt][kb]));
        }
}

__device__ __forceinline__ void load_wv(f16x8 (&wv2)[4][2][4], const half_t* w16,
                                        int base, int wv, int col, int kg) {
#pragma unroll
  for (int q = 0; q < 4; q++)
#pragma unroll
    for (int jt = 0; jt < 2; jt++)
#pragma unroll
      for (int kb = 0; kb < 4; kb++)
        wv2[q][jt][kb] = *(const f16x8*)(w16 + (size_t)(base + 2) * 65536 +
                                         (size_t)(q * 128 + wv * 32 + jt * 16 + col) * 128 +
                                         kb * 32 + kg * 8);
}

// ---------------- 8-wave fragment machinery (16 j-cols per wave) ----------------
template <int M>
__device__ __forceinline__ void pass8(f32x4 (&acc)[4], const f16x8 (&wa)[3][4][4],
                                      const half_t* buf, int col, int kg) {
#pragma unroll
  for (int kb = 0; kb < 4; kb++) {
    f16x8 a = lda(buf, col, kg, kb);
#pragma unroll
    for (int q = 0; q < 4; q++)
      mfma_a(acc[q], a, wa[M][q][kb]);
  }
}

__device__ __forceinline__ void zacc8(f32x4 (&acc)[4]) {
#pragma unroll
  for (int q = 0; q < 4; q++) acc[q] = (f32x4){0.f, 0.f, 0.f, 0.f};
}

__device__ __forceinline__ void load_w8(f16x8 (&wa)[3][4][4], const half_t* w16,
                                        int base, int wv, int col, int kg) {
#pragma unroll
  for (int m = 0; m < 3; m++)
#pragma unroll
    for (int q = 0; q < 4; q++)
#pragma unroll
      for (int kb = 0; kb < 4; kb++) {
        wa[m][q][kb] = *(const f16x8*)(w16 + (size_t)(base + m) * 65536 +
                                       (size_t)(q * 128 + wv * 16 + col) * 128 +
                                       kb * 32 + kg * 8);
        asm("" : "+a"(wa[m][q][kb]));
      }
}

// prep: fp32->fp16 weights (6 x [512][128]) + transposed combined biases biasT[set][j][4]
// + transposed input-weight cols xwT[phase][j][4]
__global__ void prep_kernel(const float* m0, const float* m1, const float* m2,
                            const float* m3, const float* m4, const float* m5,
                            const float* ba0, const float* bb0, const float* ba1, const float* bb1,
                            const float* ba2, const float* bb2, const float* ba3, const float* bb3,
                            const float* encWih0, const float* decWih0,
                            half_t* w16, float* biasT, float* xwT) {
  int i = blockIdx.x * 256 + threadIdx.x;
  if (i < 6 * 65536) {
    int m = i >> 16, e = i & 65535;
    const float* src = (m == 0) ? m0 : (m == 1) ? m1 : (m == 2) ? m2
                     : (m == 3) ? m3 : (m == 4) ? m4 : m5;
    w16[i] = (half_t)src[e];
  }
  if (i < 2048) {
    int set = i >> 9, wi = i & 511, q = wi >> 7, jh = wi & 127;
    const float* A  = (set == 0) ? ba0 : (set == 1) ? ba1 : (set == 2) ? ba2 : ba3;
    const float* Bv = (set == 0) ? bb0 : (set == 1) ? bb1 : (set == 2) ? bb2 : bb3;
    biasT[set * 512 + jh * 4 + q] = A[wi] + Bv[wi];
  }
  if (i < 1024) {
    int ph = i >> 9, wi = i & 511, q = wi >> 7, jh = wi & 127;
    xwT[ph * 512 + jh * 4 + q] = (ph ? decWih0 : encWih0)[wi];
  }
}

// ======================= r17 verified kernel (fallback) =======================
__global__ __launch_bounds__(256, 1)
void lstm_all(const float* __restrict__ x, const float* __restrict__ linW,
              const float* __restrict__ linb, const half_t* __restrict__ w16,
              const float* __restrict__ biasTg, const float* __restrict__ xwTg,
              float* __restrict__ out)
{
  __shared__ alignas(16) half_t h0b[2][BT * H];
  __shared__ alignas(16) half_t h1b[2][BT * H];
  __shared__ float xch[64 * BT];
  __shared__ float h1f[BT * H];
  __shared__ float linWs[H];
  __shared__ float pp[256];
  __shared__ float predbuf[BT];

  const int tid  = threadIdx.x;
  const int wv   = tid >> 6;
  const int lane = tid & 63;
  const int col  = lane & 15;
  const int kg   = lane >> 4;
  const int b0   = blockIdx.x * BT;

  for (int z = tid; z < 1024; z += 256) {
    ((unsigned*)h0b)[z] = 0u; ((unsigned*)h1b)[z] = 0u;
  }
  if (tid < H) linWs[tid] = linW[tid];

  f16x8 wa[2][4][2][4];
  f16x8 wv2[4][2][4];
  load_wa(wa, w16, 0, wv, col, kg);
  load_wv(wv2, w16, 0, wv, col, kg);

  float b0r[2][4], b1r[2][4], xwr[2][4];
#pragma unroll
  for (int jt = 0; jt < 2; jt++) {
    const int jj = wv * 32 + jt * 16 + col;
#pragma unroll
    for (int q = 0; q < 4; q++) {
      b0r[jt][q] = biasTg[jj * 4 + q];
      b1r[jt][q] = biasTg[512 + jj * 4 + q];
      xwr[jt][q] = xwTg[jj * 4 + q];
    }
  }

  float c0[2][2] = {{0, 0}, {0, 0}};
  float c1[2][2] = {{0, 0}, {0, 0}};

  for (int e = tid; e < BT * 64; e += 256) {
    int b = e >> 6, j = e & 63;
    xch[j * 8 + b] = x[(size_t)(b0 + b) * T + j];
  }
  __syncthreads();

  {
    f32x4 acc[2][4];
    zacc(acc);
    pass_a<0>(acc, wa, h0b[0], col, kg);
#pragma unroll
    for (int jt = 0; jt < 2; jt++) {
      const int jj = wv * 32 + jt * 16 + col;
#pragma unroll
      for (int s = 0; s < 2; s++) {
        const int b = 2 * kg + s;
        const int e = 2 * s;
        float xv = xch[0 * 8 + b];
        float gi = acc[jt][0][e] + b0r[jt][0] + xv * xwr[jt][0];
        float gf = acc[jt][1][e] + b0r[jt][1] + xv * xwr[jt][1];
        float gg = acc[jt][2][e] + b0r[jt][2] + xv * xwr[jt][2];
        float go = acc[jt][3][e] + b0r[jt][3] + xv * xwr[jt][3];
        float cn = sigm(gf) * c0[jt][s] + sigm(gi) * tanh_f(gg);
        c0[jt][s] = cn;
        wr_h(h0b[1], b, jj, sigm(go) * tanh_f(cn));
      }
    }
  }
  __syncthreads();
  int p = 1;

  for (int S = 0; S < 511; S++) {
    if (((S + 1) & 63) == 0) {
      const int ch = (S + 1) >> 6;
      for (int e = tid; e < BT * 64; e += 256) {
        int b = e >> 6, j = e & 63;
        xch[j * 8 + b] = x[(size_t)(b0 + b) * T + ch * 64 + j];
      }
      __syncthreads();
    }
    const int np = p ^ 1;
    f32x4 acc[2][4];
    zacc(acc);
    pass_v(acc, wv2, h1b[p], col, kg);
    pass_a<1>(acc, wa, h0b[p], col, kg);
#pragma unroll
    for (int jt = 0; jt < 2; jt++) {
      const int jj = wv * 32 + jt * 16 + col;
#pragma unroll
      for (int s = 0; s < 2; s++) {
        const int b = 2 * kg + s;
        const int e = 2 * s;
        float gi = acc[jt][0][e] + b1r[jt][0];
        float gf = acc[jt][1][e] + b1r[jt][1];
        float gg = acc[jt][2][e] + b1r[jt][2];
        float go = acc[jt][3][e] + b1r[jt][3];
        float cn = sigm(gf) * c1[jt][s] + sigm(gi) * tanh_f(gg);
        c1[jt][s] = cn;
        wr_h(h1b[np], b, jj, sigm(go) * tanh_f(cn));
      }
    }
    zacc(acc);
    pass_a<0>(acc, wa, h0b[p], col, kg);
#pragma unroll
    for (int jt = 0; jt < 2; jt++) {
      const int jj = wv * 32 + jt * 16 + col;
#pragma unroll
      for (int s = 0; s < 2; s++) {
        const int b = 2 * kg + s;
        const int e = 2 * s;
        float xv = xch[((S + 1) & 63) * 8 + b];
        float gi = acc[jt][0][e] + b0r[jt][0] + xv * xwr[jt][0];
        float gf = acc[jt][1][e] + b0r[jt][1] + xv * xwr[jt][1];
        float gg = acc[jt][2][e] + b0r[jt][2] + xv * xwr[jt][2];
        float go = acc[jt][3][e] + b0r[jt][3] + xv * xwr[jt][3];
        float cn = sigm(gf) * c0[jt][s] + sigm(gi) * tanh_f(gg);
        c0[jt][s] = cn;
        wr_h(h0b[np], b, jj, sigm(go) * tanh_f(cn));
      }
    }
    __syncthreads();
    p = np;
  }

  {
    const int np = p ^ 1;
    f32x4 acc[2][4];
    zacc(acc);
    pass_v(acc, wv2, h1b[p], col, kg);
    pass_a<1>(acc, wa, h0b[p], col, kg);
#pragma unroll
    for (int jt = 0; jt < 2; jt++) {
      const int jj = wv * 32 + jt * 16 + col;
#pragma unroll
      for (int s = 0; s < 2; s++) {
        const int b = 2 * kg + s;
        const int e = 2 * s;
        float gi = acc[jt][0][e] + b1r[jt][0];
        float gf = acc[jt][1][e] + b1r[jt][1];
        float gg = acc[jt][2][e] + b1r[jt][2];
        float go = acc[jt][3][e] + b1r[jt][3];
        float cn = sigm(gf) * c1[jt][s] + sigm(gi) * tanh_f(gg);
        c1[jt][s] = cn;
        wr_h(h1b[np], b, jj, sigm(go) * tanh_f(cn));
      }
    }
    __syncthreads();
  }
  int p0 = p;
  int p1 = p ^ 1;

  load_wa(wa, w16, 3, wv, col, kg);
  load_wv(wv2, w16, 3, wv, col, kg);
#pragma unroll
  for (int jt = 0; jt < 2; jt++) {
    const int jj = wv * 32 + jt * 16 + col;
#pragma unroll
    for (int q = 0; q < 4; q++) {
      b0r[jt][q] = biasTg[1024 + jj * 4 + q];
      b1r[jt][q] = biasTg[1536 + jj * 4 + q];
      xwr[jt][q] = xwTg[512 + jj * 4 + q];
    }
  }
  const float lb = linb[0];
  if (tid < BT) predbuf[tid] = x[(size_t)(b0 + tid) * T + (T - 1)];
  __syncthreads();

  for (int so = 0; so < OUTS; so++) {
    const int n0 = p0 ^ 1, n1 = p1 ^ 1;
    f32x4 acc[2][4];
    zacc(acc);
    pass_a<0>(acc, wa, h0b[p0], col, kg);
#pragma unroll
    for (int jt = 0; jt < 2; jt++) {
      const int jj = wv * 32 + jt * 16 + col;
#pragma unroll
      for (int s = 0; s < 2; s++) {
        const int b = 2 * kg + s;
        const int e = 2 * s;
        float xv = predbuf[b];
        float gi = acc[jt][0][e] + b0r[jt][0] + xv * xwr[jt][0];
        float gf = acc[jt][1][e] + b0r[jt][1] + xv * xwr[jt][1];
        float gg = acc[jt][2][e] + b0r[jt][2] + xv * xwr[jt][2];
        float go = acc[jt][3][e] + b0r[jt][3] + xv * xwr[jt][3];
        float cn = sigm(gf) * c0[jt][s] + sigm(gi) * tanh_f(gg);
        c0[jt][s] = cn;
        wr_h(h0b[n0], b, jj, sigm(go) * tanh_f(cn));
      }
    }
    __syncthreads();
    zacc(acc);
    pass_v(acc, wv2, h1b[p1], col, kg);
    pass_a<1>(acc, wa, h0b[n0], col, kg);
#pragma unroll
    for (int jt = 0; jt < 2; jt++) {
      const int jj = wv * 32 + jt * 16 + col;
#pragma unroll
      for (int s = 0; s < 2; s++) {
        const int b = 2 * kg + s;
        const int e = 2 * s;
        float cn = sigm(acc[jt][1][e] + b1r[jt][1]) * c1[jt][s]
                 + sigm(acc[jt][0][e] + b1r[jt][0]) * tanh_f(acc[jt][2][e] + b1r[jt][2]);
        c1[jt][s] = cn;
        float hn = sigm(acc[jt][3][e] + b1r[jt][3]) * tanh_f(cn);
        wr_h(h1b[n1], b, jj, hn);
        h1f[b * H + jj] = hn;
      }
    }
    __syncthreads();
    {
      int r = tid >> 5, seg = tid & 31;
      float pv = 0.0f;
#pragma unroll
      for (int kk = 0; kk < 4; kk++) pv += h1f[r * H + seg * 4 + kk] * linWs[seg * 4 + kk];
      pp[tid] = pv;
    }
    __syncthreads();
    if (tid < BT) {
      float pv = lb;
#pragma unroll
      for (int g2 = 0; g2 < 32; g2++) pv += pp[tid * 32 + g2];
      predbuf[tid] = pv;
      out[(size_t)(b0 + tid) * OUTS + so] = pv;
    }
    __syncthreads();
    p0 = n0; p1 = n1;
  }
}

// ======================= 8-wave / 2-per-SIMD variant =======================
__global__ __launch_bounds__(512, 2)
void lstm_all8(const float* __restrict__ x, const float* __restrict__ linW,
               const float* __restrict__ linb, const half_t* __restrict__ w16,
               const float* __restrict__ biasTg, const float* __restrict__ xwTg,
               float* __restrict__ out)
{
  __shared__ alignas(16) half_t h0b[2][BT * H];
  __shared__ alignas(16) half_t h1b[2][BT * H];
  __shared__ float xch[64 * BT];
  __shared__ float h1f[BT * H];
  __shared__ float linWs[H];
  __shared__ float pp[256];
  __shared__ float predbuf[BT];

  const int tid  = threadIdx.x;
  const int wv   = tid >> 6;         // 0..7, owns j in [16wv, 16wv+16)
  const int lane = tid & 63;
  const int col  = lane & 15;
  const int kg   = lane >> 4;
  const int b0   = blockIdx.x * BT;

  for (int z = tid; z < 1024; z += 512) {
    ((unsigned*)h0b)[z] = 0u; ((unsigned*)h1b)[z] = 0u;
  }
  if (tid < H) linWs[tid] = linW[tid];

  // all three matrices AGPR-pinned: {Whh0, Wih1, Whh1} = 192 AGPRs
  f16x8 wa[3][4][4];
  load_w8(wa, w16, 0, wv, col, kg);

  float b0r[4], b1r[4], xwr[4];
  {
    const int jj = wv * 16 + col;
#pragma unroll
    for (int q = 0; q < 4; q++) {
      b0r[q] = biasTg[jj * 4 + q];
      b1r[q] = biasTg[512 + jj * 4 + q];
      xwr[q] = xwTg[jj * 4 + q];
    }
  }

  float c0[2] = {0, 0};
  float c1[2] = {0, 0};

  for (int e = tid; e < BT * 64; e += 512) {
    int b = e >> 6, j = e & 63;
    xch[j * 8 + b] = x[(size_t)(b0 + b) * T + j];
  }
  __syncthreads();

  // prologue: cell0 t=0
  {
    f32x4 acc[4];
    zacc8(acc);
    pass8<0>(acc, wa, h0b[0], col, kg);
    const int jj = wv * 16 + col;
#pragma unroll
    for (int s = 0; s < 2; s++) {
      const int b = 2 * kg + s;
      const int e = 2 * s;
      float xv = xch[0 * 8 + b];
      float gi = acc[0][e] + b0r[0] + xv * xwr[0];
      float gf = acc[1][e] + b0r[1] + xv * xwr[1];
      float gg = acc[2][e] + b0r[2] + xv * xwr[2];
      float go = acc[3][e] + b0r[3] + xv * xwr[3];
      float cn = sigm(gf) * c0[s] + sigm(gi) * tanh_f(gg);
      c0[s] = cn;
      wr_h(h0b[1], b, jj, sigm(go) * tanh_f(cn));
    }
  }
  __syncthreads();
  int p = 1;

  // merged super-steps: cell1(t=S) + cell0(t=S+1), 1 barrier
  for (int S = 0; S < 511; S++) {
    if (((S + 1) & 63) == 0) {
      const int ch = (S + 1) >> 6;
      for (int e = tid; e < BT * 64; e += 512) {
        int b = e >> 6, j = e & 63;
        xch[j * 8 + b] = x[(size_t)(b0 + b) * T + ch * 64 + j];
      }
      __syncthreads();
    }
    const int np = p ^ 1;
    f32x4 acc[4];
    zacc8(acc);
    pass8<2>(acc, wa, h1b[p], col, kg);   // Whh1 * h1[S-1]
    pass8<1>(acc, wa, h0b[p], col, kg);   // Wih1 * h0[S]
    {
      const int jj = wv * 16 + col;
#pragma unroll
      for (int s = 0; s < 2; s++) {
        const int b = 2 * kg + s;
        const int e = 2 * s;
        float gi = acc[0][e] + b1r[0];
        float gf = acc[1][e] + b1r[1];
        float gg = acc[2][e] + b1r[2];
        float go = acc[3][e] + b1r[3];
        float cn = sigm(gf) * c1[s] + sigm(gi) * tanh_f(gg);
        c1[s] = cn;
        wr_h(h1b[np], b, jj, sigm(go) * tanh_f(cn));
      }
    }
    zacc8(acc);
    pass8<0>(acc, wa, h0b[p], col, kg);   // Whh0 * h0[S]
    {
      const int jj = wv * 16 + col;
#pragma unroll
      for (int s = 0; s < 2; s++) {
        const int b = 2 * kg + s;
        const int e = 2 * s;
        float xv = xch[((S + 1) & 63) * 8 + b];
        float gi = acc[0][e] + b0r[0] + xv * xwr[0];
        float gf = acc[1][e] + b0r[1] + xv * xwr[1];
        float gg = acc[2][e] + b0r[2] + xv * xwr[2];
        float go = acc[3][e] + b0r[3] + xv * xwr[3];
        float cn = sigm(gf) * c0[s] + sigm(gi) * tanh_f(gg);
        c0[s] = cn;
        wr_h(h0b[np], b, jj, sigm(go) * tanh_f(cn));
      }
    }
    __syncthreads();
    p = np;
  }

  // epilogue: cell1 t=511
  {
    const int np = p ^ 1;
    f32x4 acc[4];
    zacc8(acc);
    pass8<2>(acc, wa, h1b[p], col, kg);
    pass8<1>(acc, wa, h0b[p], col, kg);
    const int jj = wv * 16 + col;
#pragma unroll
    for (int s = 0; s < 2; s++) {
      const int b = 2 * kg + s;
      const int e = 2 * s;
      float gi = acc[0][e] + b1r[0];
      float gf = acc[1][e] + b1r[1];
      float gg = acc[2][e] + b1r[2];
      float go = acc[3][e] + b1r[3];
      float cn = sigm(gf) * c1[s] + sigm(gi) * tanh_f(gg);
      c1[s] = cn;
      wr_h(h1b[np], b, jj, sigm(go) * tanh_f(cn));
    }
    __syncthreads();
  }
  int p0 = p;
  int p1 = p ^ 1;

  // decoder
  load_w8(wa, w16, 3, wv, col, kg);
  {
    const int jj = wv * 16 + col;
#pragma unroll
    for (int q = 0; q < 4; q++) {
      b0r[q] = biasTg[1024 + jj * 4 + q];
      b1r[q] = biasTg[1536 + jj * 4 + q];
      xwr[q] = xwTg[512 + jj * 4 + q];
    }
  }
  const float lb = linb[0];
  if (tid < BT) predbuf[tid] = x[(size_t)(b0 + tid) * T + (T - 1)];
  __syncthreads();

  for (int so = 0; so < OUTS; so++) {
    const int n0 = p0 ^ 1, n1 = p1 ^ 1;
    f32x4 acc[4];
    zacc8(acc);
    pass8<0>(acc, wa, h0b[p0], col, kg);
    {
      const int jj = wv * 16 + col;
#pragma unroll
      for (int s = 0; s < 2; s++) {
        const int b = 2 * kg + s;
        const int e = 2 * s;
        float xv = predbuf[b];
        float gi = acc[0][e] + b0r[0] + xv * xwr[0];
        float gf = acc[1][e] + b0r[1] + xv * xwr[1];
        float gg = acc[2][e] + b0r[2] + xv * xwr[2];
        float go = acc[3][e] + b0r[3] + xv * xwr[3];
        float cn = sigm(gf) * c0[s] + sigm(gi) * tanh_f(gg);
        c0[s] = cn;
        wr_h(h0b[n0], b, jj, sigm(go) * tanh_f(cn));
      }
    }
    __syncthreads();
    zacc8(acc);
    pass8<2>(acc, wa, h1b[p1], col, kg);
    pass8<1>(acc, wa, h0b[n0], col, kg);
    {
      const int jj = wv * 16 + col;
#pragma unroll
      for (int s = 0; s < 2; s++) {
        const int b = 2 * kg + s;
        const int e = 2 * s;
        float cn = sigm(acc[1][e] + b1r[1]) * c1[s]
                 + sigm(acc[0][e] + b1r[0]) * tanh_f(acc[2][e] + b1r[2]);
        c1[s] = cn;
        float hn = sigm(acc[3][e] + b1r[3]) * tanh_f(cn);
        wr_h(h1b[n1], b, jj, hn);
        h1f[b * H + jj] = hn;
      }
    }
    __syncthreads();
    if (tid < 256) {
      int r = tid >> 5, seg = tid & 31;
      float pv = 0.0f;
#pragma unroll
      for (int kk = 0; kk < 4; kk++) pv += h1f[r * H + seg * 4 + kk] * linWs[seg * 4 + kk];
      pp[tid] = pv;
    }
    __syncthreads();
    if (tid < BT) {
      float pv = lb;
#pragma unroll
      for (int g2 = 0; g2 < 32; g2++) pv += pp[tid * 32 + g2];
      predbuf[tid] = pv;
      out[(size_t)(b0 + tid) * OUTS + so] = pv;
    }
    __syncthreads();
    p0 = n0; p1 = n1;
  }
}

extern "C" void kernel_launch(void* const* d_in, const int* in_sizes, int n_in,
                              void* d_out, int out_size, void* d_ws, size_t ws_size,
                              hipStream_t stream) {
  const float* x        = (const float*)d_in[0];
  const float* encWih0  = (const float*)d_in[1];
  const float* encWhh0  = (const float*)d_in[2];
  const float* encbih0  = (const float*)d_in[3];
  const float* encbhh0  = (const float*)d_in[4];
  const float* encWih1  = (const float*)d_in[5];
  const float* encWhh1  = (const float*)d_in[6];
  const float* encbih1  = (const float*)d_in[7];
  const float* encbhh1  = (const float*)d_in[8];
  const float* decWih0  = (const float*)d_in[9];
  const float* decWhh0  = (const float*)d_in[10];
  const float* decbih0  = (const float*)d_in[11];
  const float* decbhh0  = (const float*)d_in[12];
  const float* decWih1  = (const float*)d_in[13];
  const float* decWhh1  = (const float*)d_in[14];
  const float* decbih1  = (const float*)d_in[15];
  const float* decbhh1  = (const float*)d_in[16];
  const float* linW     = (const float*)d_in[17];
  const float* linb     = (const float*)d_in[18];

  half_t* w16  = (half_t*)d_ws;                                   // 786432 B
  float*  biasT = (float*)((char*)d_ws + (size_t)6 * 65536 * 2);  // 2048 f32
  float*  xwT   = biasT + 2048;                                   // 1024 f32

  prep_kernel<<<1536, 256, 0, stream>>>(encWhh0, encWih1, encWhh1, decWhh0, decWih1, decWhh1,
                                        encbih0, encbhh0, encbih1, encbhh1,
                                        decbih0, decbhh0, decbih1, decbhh1,
                                        encWih0, decWih0, w16, biasT, xwT);

  // Guarded dispatch: use the 8-wave variant only if it compiled spill-free and is
  // actually launchable (r16's silent-zero failure = launch out of resources).
  static int use8 = -1;
  if (use8 < 0) {
    hipFuncAttributes attr{};
    int occ = 0;
    hipError_t e1 = hipFuncGetAttributes(&attr, (const void*)lstm_all8);
    hipError_t e2 = hipOccupancyMaxActiveBlocksPerMultiprocessor(&occ, (const void*)lstm_all8,
                                                                 512, 0);
    use8 = (e1 == hipSuccess && e2 == hipSuccess && occ >= 1 && attr.localSizeBytes == 0) ? 1 : 0;
  }
  if (use8)
    lstm_all8<<<256, 512, 0, stream>>>(x, linW, linb, w16, biasT, xwT, (float*)d_out);
  else
    lstm_all<<<256, 256, 0, stream>>>(x, linW, linb, w16, biasT, xwT, (float*)d_out);
}